// Round 4
// baseline (4021.347 us; speedup 1.0000x reference)
//
#include <hip/hip_runtime.h>
#include <hip/hip_fp16.h>

// MLPProjectionFilter: merged-iteration MFMA design (round-3 structure,
// round-4 fix: symbolic ws offsets — rhs buffer was undersized by 512 floats,
// causing rhsH/rhsL/sqP overlap and absmax 11.7).
// Identities: u=min(v,b)=v-rs, rs=relu(v-b); G = sum_m A^T u = Mall*x - dl_sum,
// Mall = sum_m A_m^T A_m (precomputed). Per iteration ONE kernel kK:
//   phase A (j-quarter per chunk-WG): dl-sum, S/lambda update, rhs build -> global,
//   per-tile counter barrier, QTinv MFMA -> primal, then fwd (v=Ax) + transpose
//   (dl = A^T rs) with split-bf16 3-product MFMA (independent accumulators).
// blockIdx = tile*4+chunk (tile's WGs co-launch -> barrier deadlock-free).

typedef short s16x8 __attribute__((ext_vector_type(8)));
typedef float f32x4 __attribute__((ext_vector_type(4)));
#define MFMA(a,b,c) __builtin_amdgcn_mfma_f32_16x16x32_bf16(a,b,c,0,0,0)

#define B2 2048
#define NV 192
#define NTT 222
#define KPAD 232
#define NTIL 128
#define RBC 20        // fwd 16-row blocks per chunk
#define KKC 10        // transpose 32-k blocks per chunk
#define PR 328        // rs LDS pitch (ushort)
#define PPX 204       // pxL pitch (f32)
#define PMX 49        // mxL pitch (f32)

// ---- ws layout (float offsets), all symbolic ----
#define SZ_SC   ((unsigned)(NV*B2))            // 393,216
#define SZ_UF   ((unsigned)(3*1200*B2/2))      // f16 u in float units: 3,686,400
#define SZ_DLF  ((unsigned)(4*576*B2))         // 4,718,592
#define SZ_RHF  ((unsigned)(B2*KPAD/2))        // 237,568  (was wrongly 237,056)
#define SZ_SQPF ((unsigned)(4*B2*8))           // 65,536
#define SZ_SQDF ((unsigned)(2*4*B2*4))         // 65,536 (two 32,768 halves)
#define SZ_AF   ((unsigned)(3*80*6*512/2))     // 368,640
#define SZ_QF   ((unsigned)(12*7*512/2))       // 21,504
#define SZ_MF   ((unsigned)(12*6*512/2))       // 18,432

#define O_S0  0u
#define O_S1  (O_S0 + SZ_SC)
#define O_C0  (O_S1 + SZ_SC)
#define O_C1  (O_C0 + SZ_SC)
#define O_U   (O_C1 + SZ_SC)
#define O_DL  (O_U + SZ_UF)
#define O_RH  (O_DL + SZ_DLF)
#define O_RL  (O_RH + SZ_RHF)
#define O_SQP (O_RL + SZ_RHF)
#define O_SQD (O_SQP + SZ_SQPF)
#define O_TOT (O_SQD + SZ_SQDF)
#define O_CNT (O_TOT + 2u*B2)
#define O_AH  (O_CNT + 128u)
#define O_AL  (O_AH + SZ_AF)
#define O_ATH (O_AL + SZ_AF)
#define O_ATL (O_ATH + SZ_AF)
#define O_QTH (O_ATL + SZ_AF)
#define O_QTL (O_QTH + SZ_QF)
#define O_MH  (O_QTL + SZ_QF)
#define O_ML2 (O_MH + SZ_MF)
#define O_MT  (O_ML2 + SZ_MF)
#define WS_FLOATS (O_MT + (unsigned)(NV*NV))   // 12,179,584 fl = 48.7 MB

__device__ inline unsigned short bh16(float v){
  union{float f; unsigned u;} a; a.f=v;
  return (unsigned short)((a.u + 0x7FFFu + ((a.u>>16)&1u))>>16);
}
__device__ inline void bsplit2(float v, unsigned short& h, unsigned short& l){
  h = bh16(v);
  union{unsigned u; float f;} hf; hf.u = ((unsigned)h)<<16;
  l = bh16(v - hf.f);
}
__device__ inline void split8(const float* x, s16x8& H, s16x8& L){
  #pragma unroll
  for (int e=0;e<8;++e){ unsigned short h,l; bsplit2(x[e],h,l); H[e]=(short)h; L[e]=(short)l; }
}

__global__ __launch_bounds__(256) void kz(float* __restrict__ ws, int n1, int n2) {
  int idx = blockIdx.x*256 + threadIdx.x;
  if (idx < n1) { ws[O_DL + idx] = 0.f; return; }
  idx -= n1;
  if (idx < n2) ws[O_MT + idx] = 0.f;
}

// Mall = sum_m A_m^T A_m (r-split x4, atomicAdd combine)
__global__ __launch_bounds__(256) void kM(const float* __restrict__ Av,
    const float* __restrict__ Aa, const float* __restrict__ Ap, float* __restrict__ M) {
  int bb = blockIdx.x % 144, part = blockIdx.x / 144;
  int idx = bb*256 + threadIdx.x;
  if (idx >= NV*NV) return;
  int i = idx / NV, j = idx - i*NV;
  float acc = 0.f;
  const int r0 = part*300;
  for (int mat=0; mat<3; ++mat) {
    const float* __restrict__ A = (mat==0)?Av:((mat==1)?Aa:Ap);
    #pragma unroll 4
    for (int r=r0; r<r0+300; ++r)
      acc = fmaf(A[(size_t)r*NV+i], A[(size_t)r*NV+j], acc);
  }
  atomicAdd(&M[idx], acc);
}

// swizzle Mall into MFMA A-frags (bf16 hi/lo)
__global__ __launch_bounds__(256) void kS(const float* __restrict__ M,
    unsigned short* __restrict__ Mh, unsigned short* __restrict__ Ml) {
  int idx = blockIdx.x*256 + threadIdx.x;
  if (idx >= 12*6*512) return;
  int jj = idx&7, lane=(idx>>3)&63, kb=(idx>>9)%6, mb=(idx>>9)/6;
  int i = mb*16 + (lane&15), k = kb*32 + (lane>>4)*8 + jj;
  unsigned short h,l; bsplit2(M[(size_t)i*NV+k], h, l);
  Mh[idx]=h; Ml[idx]=l;
}

// init: S0 = lam_v+lam_a+lam_p+cin ([192][2048]); C0 = c0^T ([192][2048]); QTinv frags
__global__ __launch_bounds__(256) void ki(const float* __restrict__ lam,
    const float* __restrict__ cin, const float* __restrict__ c0,
    const float* __restrict__ Qinv, float* __restrict__ S0, float* __restrict__ C0,
    unsigned short* __restrict__ QTh, unsigned short* __restrict__ QTl) {
  int idx = blockIdx.x*256 + threadIdx.x;
  if (idx < NV*B2) {
    int j = idx / B2, s = idx - j*B2;
    S0[idx] = lam[(size_t)s*576 + j] + lam[(size_t)s*576 + 192 + j]
            + lam[(size_t)s*576 + 384 + j] + cin[(size_t)s*NV + j];
    return;
  }
  idx -= NV*B2;
  if (idx < NV*B2) { int i = idx / B2, s = idx - i*B2; C0[idx] = c0[(size_t)s*NV + i]; return; }
  idx -= NV*B2;
  if (idx < 12*7*512) {
    int jj = idx&7, lane=(idx>>3)&63, kb=(idx>>9)%7, mb=(idx>>9)/7;
    int i = mb*16 + (lane&15), j = kb*32 + (lane>>4)*8 + jj;
    float v = (j < NTT) ? Qinv[(size_t)i*NTT + j] : 0.f;
    unsigned short h,l; bsplit2(v,h,l);
    QTh[idx]=h; QTl[idx]=l;
  }
}

// A operand swizzle (identical semantics to validated round-2 kA)
__global__ __launch_bounds__(256) void kA(const float* __restrict__ Av,
    const float* __restrict__ Aa, const float* __restrict__ Ap,
    unsigned short* __restrict__ Ah, unsigned short* __restrict__ Al,
    unsigned short* __restrict__ Ath, unsigned short* __restrict__ Atl) {
  int idx = blockIdx.x*256 + threadIdx.x;
  const int HALF = 3*80*6*512;
  if (idx >= 2*HALF) return;
  if (idx < HALF) {
    int j = idx&7, lane=(idx>>3)&63, kb=(idx>>9)%6, rb=(idx>>9)/6%80, mat=idx/(80*6*512);
    int row = rb*16 + (lane&15), col = kb*32 + (lane>>4)*8 + j;
    const float* A = (mat==0)?Av:((mat==1)?Aa:Ap);
    float v = (row < 1200) ? A[(size_t)row*NV + col] : 0.f;
    unsigned short h,l; bsplit2(v,h,l); Ah[idx]=h; Al[idx]=l;
  } else {
    int oi = idx - HALF;
    int jj = oi&7, lane=(oi>>3)&63, kbr=(oi>>9)%40, cb=(oi>>9)/40%12, mat=oi/(12*40*512);
    int row = kbr*32 + (lane>>4)*8 + jj, col = cb*16 + (lane&15);
    const float* A = (mat==0)?Av:((mat==1)?Aa:Ap);
    float v = (row < 1200) ? A[(size_t)row*NV + col] : 0.f;
    unsigned short h,l; bsplit2(v,h,l); Ath[oi]=h; Atl[oi]=l;
  }
}

// ---- the per-iteration kernel. grid = 512 (blockIdx = tile*4+chunk), block = 512.
template<int PRIME>
__global__ __launch_bounds__(512,4) void kK(
    const float* __restrict__ Sin, float* __restrict__ Sout,
    const float* __restrict__ Cin, float* __restrict__ Cout,
    const float* __restrict__ c0, const float* __restrict__ beq,
    float* __restrict__ dl,
    unsigned short* __restrict__ rhsH, unsigned short* __restrict__ rhsL,
    float* __restrict__ sqP, const float* __restrict__ sqDin, float* __restrict__ sqDout,
    float* __restrict__ tot, int* __restrict__ cnt,
    const unsigned short* __restrict__ Ah, const unsigned short* __restrict__ Al,
    const unsigned short* __restrict__ Ath, const unsigned short* __restrict__ Atl,
    const unsigned short* __restrict__ QTh, const unsigned short* __restrict__ QTl,
    const unsigned short* __restrict__ Mh, const unsigned short* __restrict__ Ml,
    __half* __restrict__ uW, int d, int upd)
{
  __shared__ unsigned short rsh[16*PR], rsl[16*PR];
  __shared__ float pxL[16*PPX];
  __shared__ float mxL[16*PMX];
  __shared__ float sqAcc[96];
  __shared__ float lamAcc[64];   // [0..47]: ||dl_m||^2 partials; [48..63]: xdiff^2
  __shared__ float fpP[16], rpP[16];

  const int tid = threadIdx.x, wave = tid>>6, lane = tid&63;
  const int n = lane&15, q = lane>>4;
  const int tile = blockIdx.x >> 2, chunk = blockIdx.x & 3;
  const int tile0 = tile*16, ts = tile0 + n;

  if (tid < 96) sqAcc[tid] = 0.f;
  if (tid < 64) lamAcc[tid] = 0.f;

  s16x8 xfh[6], xfl[6];

  if (PRIME) {
    #pragma unroll
    for (int kb=0;kb<6;++kb) {
      float xv[8];
      const float* p = c0 + (size_t)(tile0+n)*NV + kb*32 + q*8;
      #pragma unroll
      for (int e=0;e<8;++e) xv[e] = p[e];
      split8(xv, xfh[kb], xfl[kb]);
    }
  } else {
    // ---- phase A0: x_{t-1} frags + Mall*x (waves 0..2) ----
    #pragma unroll
    for (int kb=0;kb<6;++kb) {
      float xv[8];
      #pragma unroll
      for (int e=0;e<8;++e) xv[e] = Cin[(size_t)(kb*32+q*8+e)*B2 + ts];
      split8(xv, xfh[kb], xfl[kb]);
    }
    if (wave < 3) {
      const int mb = chunk*3 + wave;
      f32x4 a0={0,0,0,0}, a1={0,0,0,0}, a2={0,0,0,0};
      #pragma unroll
      for (int kb=0;kb<6;++kb) {
        s16x8 mh = *(const s16x8*)(Mh + ((size_t)(mb*6+kb))*512 + lane*8);
        s16x8 ml = *(const s16x8*)(Ml + ((size_t)(mb*6+kb))*512 + lane*8);
        a0 = MFMA(mh, xfh[kb], a0);
        a1 = MFMA(mh, xfl[kb], a1);
        a2 = MFMA(ml, xfh[kb], a2);
      }
      #pragma unroll
      for (int r=0;r<4;++r) mxL[n*PMX + wave*16 + q*4 + r] = a0[r]+a1[r]+a2[r];
    }
    // finalize part1 (iter d-1 res/sd + xdiff): chunk0, wave7
    if (chunk==0 && tid>=448 && tid<464) {
      int s = tid-448, sg = tile0+s;
      float fp=0.f, rp=0.f;
      #pragma unroll
      for (int sl=0;sl<6;++sl) {
        float v = sqP[(size_t)sg*8+sl] + sqP[16384+(size_t)sg*8+sl]
                + sqP[2*16384+(size_t)sg*8+sl] + sqP[3*16384+(size_t)sg*8+sl];
        float nn = sqrtf(v);
        if (sl<3) rp += nn; else fp += nn;
      }
      fp += sqrtf(sqDin[(size_t)sg*4+3]);
      fpP[s]=fp; rpP[s]=rp;
    }
    __syncthreads();
    // ---- phase A1: j-quarter rhs/S/lambda ----
    #pragma unroll 1
    for (int p=0;p<2;++p) {
      const int jj = (tid>>4) + p*32;
      const int s = tid & 15;
      if (jj < 48) {
        const int j = chunk*48 + jj;
        const int sg = tile0 + s;
        float dm[3];
        #pragma unroll
        for (int m=0;m<3;++m) {
          float v = 0.f;
          #pragma unroll
          for (int c=0;c<4;++c) v += dl[((size_t)c*576 + m*NV + j)*B2 + sg];
          dm[m]=v;
        }
        const float dsum = dm[0]+dm[1]+dm[2];
        const float Sc = Sin[(size_t)j*B2 + sg];
        const float Sn = upd ? (Sc - dsum) : Sc;
        Sout[(size_t)j*B2 + sg] = Sn;
        const float rv = Sn + mxL[s*PMX + jj] - dsum;   // = S_new + G
        unsigned short h,l; bsplit2(rv,h,l);
        const size_t ro = (size_t)(tile*16+s)*KPAD + j;
        rhsH[ro]=h; rhsL[ro]=l;
        if (upd) {
          atomicAdd(&lamAcc[s],      dm[0]*dm[0]);
          atomicAdd(&lamAcc[16+s],   dm[1]*dm[1]);
          atomicAdd(&lamAcc[32+s],   dm[2]*dm[2]);
        }
      }
    }
    if (chunk==3 && tid < 480) {
      int je = tid>>4, s = tid&15;
      unsigned short h,l; bsplit2(beq[(size_t)(tile0+s)*30 + je], h, l);
      size_t ro = (size_t)(tile*16+s)*KPAD + NV + je;
      rhsH[ro]=h; rhsL[ro]=l;
    }
    __syncthreads();
    if (tid < 48) {
      int m = tid>>4, s = tid&15;
      sqDout[(size_t)chunk*8192 + (size_t)(tile0+s)*4 + m] = lamAcc[m*16+s];
    }
    __threadfence();
    __syncthreads();
    if (tid==0) {
      __hip_atomic_fetch_add(&cnt[tile], 1, __ATOMIC_RELEASE, __HIP_MEMORY_SCOPE_AGENT);
      while (__hip_atomic_load(&cnt[tile], __ATOMIC_ACQUIRE, __HIP_MEMORY_SCOPE_AGENT) < 4*d)
        __builtin_amdgcn_s_sleep(2);
    }
    __syncthreads();
    __threadfence();
    // finalize part2: lambda norms of iter d-1 (all quarters published)
    if (chunk==0 && tid<16) {
      int s = tid, sg = tile0+s;
      float fp = fpP[s];
      #pragma unroll
      for (int m=0;m<3;++m) {
        float v = sqDout[(size_t)sg*4+m] + sqDout[8192+(size_t)sg*4+m]
                + sqDout[2*8192+(size_t)sg*4+m] + sqDout[3*8192+(size_t)sg*4+m];
        fp += sqrtf(v);
      }
      tot[(size_t)sg*2+0] += fp;
      tot[(size_t)sg*2+1] += rpP[s];
    }
    // ---- QTinv MFMA: primal ----
    s16x8 rfh[7], rfl[7];
    #pragma unroll
    for (int kb=0;kb<7;++kb) {
      const size_t ro = (size_t)(tile*16+n)*KPAD + kb*32 + q*8;
      rfh[kb] = *(const s16x8*)(rhsH + ro);
      rfl[kb] = *(const s16x8*)(rhsL + ro);
    }
    float xdl = 0.f;
    #pragma unroll 1
    for (int mi=0; mi<2; ++mi) {
      if (mi==1 && wave>=4) break;
      const int mb = (mi==0)? wave : 8+wave;
      f32x4 a0={0,0,0,0}, a1={0,0,0,0}, a2={0,0,0,0};
      #pragma unroll
      for (int kb=0;kb<7;++kb) {
        s16x8 qh = *(const s16x8*)(QTh + ((size_t)(mb*7+kb))*512 + lane*8);
        s16x8 ql = *(const s16x8*)(QTl + ((size_t)(mb*7+kb))*512 + lane*8);
        a0 = MFMA(qh, rfh[kb], a0);
        a1 = MFMA(qh, rfl[kb], a1);
        a2 = MFMA(ql, rfh[kb], a2);
      }
      #pragma unroll
      for (int r=0;r<4;++r) {
        const float xv = a0[r]+a1[r]+a2[r];
        const int i = mb*16 + q*4 + r;
        pxL[n*PPX + i] = xv;
        if (chunk==0) {
          const float df = xv - Cin[(size_t)i*B2 + ts];
          xdl += df*df;
          Cout[(size_t)i*B2 + ts] = xv;
        }
      }
    }
    if (chunk==0) atomicAdd(&lamAcc[48+n], xdl);
    __syncthreads();
    if (chunk==0 && tid<16)
      sqDout[(size_t)(tile0+tid)*4 + 3] = lamAcc[48+tid];
    // x_t frags
    #pragma unroll
    for (int kb=0;kb<6;++kb) {
      float xv[8];
      #pragma unroll
      for (int e=0;e<8;++e) xv[e] = pxL[n*PPX + kb*32 + q*8 + e];
      split8(xv, xfh[kb], xfl[kb]);
    }
  }

  // ---- phase B (fwd) + C (transpose) per mat ----
  #pragma unroll 1
  for (int mat=0; mat<3; ++mat) {
    const float b = (mat==0)?0.8f:((mat==1)?1.8f:3.14159265358979f);
    if (mat>0) __syncthreads();
    float rsq=0.f, ssq=0.f;
    #pragma unroll 1
    for (int ri=0; ri<3; ++ri) {
      if (ri==2 && wave>=4) break;
      const int rbl = (ri==0)? wave : ((ri==1)? 8+wave : 16+wave);
      const int rb = chunk*RBC + rbl;
      f32x4 a0={0,0,0,0}, a1={0,0,0,0}, a2={0,0,0,0};
      const size_t ab = ((size_t)(mat*80+rb)*6)*512 + (size_t)lane*8;
      #pragma unroll
      for (int kb=0;kb<6;++kb) {
        s16x8 ah = *(const s16x8*)(Ah + ab + (size_t)kb*512);
        s16x8 al = *(const s16x8*)(Al + ab + (size_t)kb*512);
        a0 = MFMA(ah, xfh[kb], a0);
        a1 = MFMA(ah, xfl[kb], a1);
        a2 = MFMA(al, xfh[kb], a2);
      }
      unsigned short rh4[4], rl4[4];
      #pragma unroll
      for (int r4=0;r4<4;++r4) {
        const float v = a0[r4]+a1[r4]+a2[r4];
        const float rs = fmaxf(v-b, 0.f);
        const float u  = fminf(v, b);
        const int r = chunk*320 + rbl*16 + q*4 + r4;
        if (r < 1200) {
          const size_t ui = ((size_t)mat*1200 + r)*B2 + ts;
          if (!PRIME) {
            const float sd = u - __half2float(uW[ui]);
            ssq += sd*sd; rsq += rs*rs;
          }
          uW[ui] = __float2half(u);
        }
        bsplit2(rs, rh4[r4], rl4[r4]);
      }
      const int lo = n*PR + rbl*16 + q*4;
      uint2 pk;
      pk.x = (unsigned)rh4[0] | ((unsigned)rh4[1]<<16);
      pk.y = (unsigned)rh4[2] | ((unsigned)rh4[3]<<16);
      *(uint2*)(rsh + lo) = pk;
      pk.x = (unsigned)rl4[0] | ((unsigned)rl4[1]<<16);
      pk.y = (unsigned)rl4[2] | ((unsigned)rl4[3]<<16);
      *(uint2*)(rsl + lo) = pk;
    }
    if (!PRIME) {
      rsq += __shfl_xor(rsq,16); rsq += __shfl_xor(rsq,32);
      ssq += __shfl_xor(ssq,16); ssq += __shfl_xor(ssq,32);
      if (q==0) {
        atomicAdd(&sqAcc[mat*16+n], rsq);
        atomicAdd(&sqAcc[(3+mat)*16+n], ssq);
      }
    }
    __syncthreads();
    #pragma unroll 1
    for (int ci=0; ci<2; ++ci) {
      if (ci==1 && wave>=4) break;
      const int cb = (ci==0)? wave : 8+wave;
      f32x4 a0={0,0,0,0}, a1={0,0,0,0}, a2={0,0,0,0};
      const size_t tb = ((size_t)((mat*12+cb)*40) + chunk*KKC)*512 + (size_t)lane*8;
      const int lb = n*PR + q*8;
      #pragma unroll 2
      for (int kk=0;kk<KKC;++kk) {
        s16x8 th = *(const s16x8*)(Ath + tb + (size_t)kk*512);
        s16x8 tl = *(const s16x8*)(Atl + tb + (size_t)kk*512);
        s16x8 rh = *(const s16x8*)(rsh + lb + kk*32);
        s16x8 rl = *(const s16x8*)(rsl + lb + kk*32);
        a0 = MFMA(th, rh, a0);
        a1 = MFMA(th, rl, a1);
        a2 = MFMA(tl, rh, a2);
      }
      #pragma unroll
      for (int r4=0;r4<4;++r4)
        dl[((size_t)chunk*576 + mat*NV + cb*16 + q*4 + r4)*B2 + ts] = a0[r4]+a1[r4]+a2[r4];
    }
  }
  __syncthreads();
  if (!PRIME && tid<96) {
    int s = tid&15, sl = tid>>4;
    sqP[(size_t)chunk*16384 + (size_t)(tile0+s)*8 + sl] = sqAcc[sl*16+s];
  }
}

// finalize iteration-15 norms + outputs
__global__ __launch_bounds__(256) void k3(const float* __restrict__ dl,
    const float* __restrict__ sqP, const float* __restrict__ sqDin,
    const float* __restrict__ Cfin, const float* __restrict__ tot, float* __restrict__ out)
{
  __shared__ float sqL[8][4];
  const int tid = threadIdx.x;
  const int sb = blockIdx.x*8;
  if (tid<32) ((float*)sqL)[tid]=0.f;
  __syncthreads();
  for (int idx=tid; idx<8*576; idx+=256) {
    int s = idx&7, e = idx>>3;
    float v = 0.f;
    #pragma unroll
    for (int c=0;c<4;++c) v += dl[((size_t)c*576 + e)*B2 + sb + s];
    atomicAdd(&sqL[s][e/NV], v*v);
  }
  for (int idx=tid; idx<8*NV; idx+=256) {
    int s = idx/NV, i = idx - s*NV;
    out[(size_t)(sb+s)*NV + i] = Cfin[(size_t)i*B2 + sb + s];
  }
  __syncthreads();
  if (tid<8) {
    int s = tid, sg = sb+s;
    float fp = sqrtf(sqL[s][0]) + sqrtf(sqL[s][1]) + sqrtf(sqL[s][2]);
    fp += sqrtf(sqDin[(size_t)sg*4+3]);
    float rp = 0.f;
    #pragma unroll
    for (int sl=0;sl<6;++sl) {
      float v = sqP[(size_t)sg*8+sl] + sqP[16384+(size_t)sg*8+sl]
              + sqP[2*16384+(size_t)sg*8+sl] + sqP[3*16384+(size_t)sg*8+sl];
      float nn = sqrtf(v);
      if (sl<3) rp += nn; else fp += nn;
    }
    fp += tot[(size_t)sg*2+0];
    rp += tot[(size_t)sg*2+1];
    out[(size_t)B2*NV + sg] = fp * (1.f/15.f);
    out[(size_t)B2*NV + B2 + sg] = rp * (1.f/15.f);
  }
}

extern "C" void kernel_launch(void* const* d_in, const int* in_sizes, int n_in,
                              void* d_out, int out_size, void* d_ws, size_t ws_size,
                              hipStream_t stream) {
  const float* lamda = (const float*)d_in[0];
  const float* cin   = (const float*)d_in[1];
  const float* c0    = (const float*)d_in[2];
  const float* beq   = (const float*)d_in[3];
  const float* Av    = (const float*)d_in[4];
  const float* Aa    = (const float*)d_in[5];
  const float* Ap    = (const float*)d_in[6];
  const float* Qinv  = (const float*)d_in[7];
  if (ws_size < (size_t)WS_FLOATS * sizeof(float)) return;

  float* ws = (float*)d_ws;
  float* S[2]  = { ws + O_S0, ws + O_S1 };
  float* C[2]  = { ws + O_C0, ws + O_C1 };
  __half* uW   = (__half*)(ws + O_U);
  float* dl    = ws + O_DL;
  unsigned short* rhsH = (unsigned short*)(ws + O_RH);
  unsigned short* rhsL = (unsigned short*)(ws + O_RL);
  float* sqP   = ws + O_SQP;
  float* sqD[2]= { ws + O_SQD, ws + O_SQD + 32768 };
  float* tot   = ws + O_TOT;
  int*   cnt   = (int*)(ws + O_CNT);
  unsigned short* Ah  = (unsigned short*)(ws + O_AH);
  unsigned short* Al  = (unsigned short*)(ws + O_AL);
  unsigned short* Ath = (unsigned short*)(ws + O_ATH);
  unsigned short* Atl = (unsigned short*)(ws + O_ATL);
  unsigned short* QTh = (unsigned short*)(ws + O_QTH);
  unsigned short* QTl = (unsigned short*)(ws + O_QTL);
  unsigned short* Mh  = (unsigned short*)(ws + O_MH);
  unsigned short* Ml  = (unsigned short*)(ws + O_ML2);
  float* MT = ws + O_MT;
  float* out = (float*)d_out;

  const int n1 = (int)(O_AH - O_DL);   // zero dl..cnt (contiguous)
  const int n2 = NV*NV;
  kz<<<(n1 + n2 + 255)/256, 256, 0, stream>>>(ws, n1, n2);
  kM<<<4*144, 256, 0, stream>>>(Av, Aa, Ap, MT);
  kS<<<(12*6*512 + 255)/256, 256, 0, stream>>>(MT, Mh, Ml);
  ki<<<(2*NV*B2 + 12*7*512 + 255)/256, 256, 0, stream>>>(lamda, cin, c0, Qinv, S[0], C[0], QTh, QTl);
  kA<<<(2*3*80*6*512 + 255)/256, 256, 0, stream>>>(Av, Aa, Ap, Ah, Al, Ath, Atl);

  // prime: u_0, dl_0 from x=c0
  kK<1><<<512, 512, 0, stream>>>(S[0], S[1], C[0], C[1], c0, beq, dl, rhsH, rhsL,
      sqP, sqD[0], sqD[1], tot, cnt, Ah, Al, Ath, Atl, QTh, QTl, Mh, Ml, uW, 0, 0);
  for (int d = 1; d <= 15; ++d) {
    kK<0><<<512, 512, 0, stream>>>(S[(d+1)&1], S[d&1], C[(d+1)&1], C[d&1], c0, beq,
        dl, rhsH, rhsL, sqP, sqD[(d+1)&1], sqD[d&1], tot, cnt,
        Ah, Al, Ath, Atl, QTh, QTl, Mh, Ml, uW, d, (d>=2)?1:0);
  }
  k3<<<256, 256, 0, stream>>>(dl, sqP, sqD[1], C[1], tot, out);
}

// Round 7
// 1360.228 us; speedup vs baseline: 2.9564x; 2.9564x over previous
//
#include <hip/hip_runtime.h>
#include <hip/hip_fp16.h>

// MLPProjectionFilter round 7 = round-6 split design made bit-deterministic:
//  - kM writes 4 partial Gram matrices (NO cross-WG float atomics); kS sums
//    them in fixed order. Round-6's atomicAdd ordering varied call-to-call and
//    the 15-iter fixed-point map amplified ~1e-7 -> 0.38 (post-timing fail).
//  - kz dropped: no ws buffer is read before being written (kP `upd` flag
//    skips sqP at d=1 and writes tot instead of accumulating).
// Per iter: kP (per-tile: dl-sum, S/lambda, G=Mall*x-dlsum, rhs, Qinv MFMA,
// norms) then k2 (A-stream: v=Ax fwd + dl=A^T rs transpose, split-bf16 MFMA).

typedef short s16x8 __attribute__((ext_vector_type(8)));
typedef float f32x4 __attribute__((ext_vector_type(4)));
#define MFMA(a,b,c) __builtin_amdgcn_mfma_f32_16x16x32_bf16(a,b,c,0,0,0)

#define B2 2048
#define NV 192
#define NTT 222
#define KPAD 232
#define PR 328        // k2 rs LDS pitch (ushort), 320 rows/chunk + pad
#define PMX 200       // kP mxL pitch (f32)

// ---- ws layout (float offsets) ----
#define O_S0  0u
#define O_S1  393216u
#define O_C0  786432u
#define O_C1  1179648u
#define O_U   1572864u     // __half[3*1200*2048] = 3,686,400 fl
#define O_DL  5259264u     // f32 [4][576][2048] = 4,718,592
#define O_SQP 9977856u     // f32 [4][2048][8] = 65,536
#define O_TOT 10043392u    // f32 [2048][2] = 4,096
#define O_XH  10047488u    // ushort[2048*192] = 196,608 fl
#define O_XL  10244096u
#define O_AH  10440704u    // ushort[3*80*6*512] = 368,640 fl each
#define O_AL  10809344u
#define O_ATH 11177984u
#define O_ATL 11546624u
#define O_QTH 11915264u    // ushort[12*7*512] = 21,504 fl
#define O_QTL 11936768u
#define O_MH  11958272u    // ushort[12*6*512] = 18,432 fl
#define O_ML2 11976704u
#define O_MP  11995136u    // f32 [4][192*192] Gram partials = 147,456
#define WS_FLOATS 12142592u  // 48.6 MB

__device__ inline unsigned short bh16(float v){
  union{float f; unsigned u;} a; a.f=v;
  return (unsigned short)((a.u + 0x7FFFu + ((a.u>>16)&1u))>>16);
}
__device__ inline void bsplit2(float v, unsigned short& h, unsigned short& l){
  h = bh16(v);
  union{unsigned u; float f;} hf; hf.u = ((unsigned)h)<<16;
  l = bh16(v - hf.f);
}

// Gram partials: MP[part][i*NV+j] = sum over rows [part*300, part*300+300) of
// sum_m A_m[r][i]*A_m[r][j]. Deterministic (no atomics).
__global__ __launch_bounds__(256) void kM(const float* __restrict__ Av,
    const float* __restrict__ Aa, const float* __restrict__ Ap, float* __restrict__ MP) {
  int bb = blockIdx.x % 144, part = blockIdx.x / 144;
  int idx = bb*256 + threadIdx.x;
  if (idx >= NV*NV) return;
  int i = idx / NV, j = idx - i*NV;
  float acc = 0.f;
  const int r0 = part*300;
  for (int mat=0; mat<3; ++mat) {
    const float* __restrict__ A = (mat==0)?Av:((mat==1)?Aa:Ap);
    #pragma unroll 4
    for (int r=r0; r<r0+300; ++r)
      acc = fmaf(A[(size_t)r*NV+i], A[(size_t)r*NV+j], acc);
  }
  MP[(size_t)part*NV*NV + idx] = acc;
}

// sum Gram partials (fixed order) and swizzle into MFMA A-frags (bf16 hi/lo)
__global__ __launch_bounds__(256) void kS(const float* __restrict__ MP,
    unsigned short* __restrict__ Mh, unsigned short* __restrict__ Ml) {
  int idx = blockIdx.x*256 + threadIdx.x;
  if (idx >= 12*6*512) return;
  int jj = idx&7, lane=(idx>>3)&63, kb=(idx>>9)%6, mb=(idx>>9)/6;
  int i = mb*16 + (lane&15), k = kb*32 + (lane>>4)*8 + jj;
  const size_t e = (size_t)i*NV + k;
  float v = MP[e] + MP[(size_t)NV*NV + e] + MP[2*(size_t)NV*NV + e] + MP[3*(size_t)NV*NV + e];
  unsigned short h,l; bsplit2(v, h, l);
  Mh[idx]=h; Ml[idx]=l;
}

// init: S0 = lamv+lama+lamp+cin [192][2048]; C0 = c0^T [192][2048];
// xh/xl = split(c0) [s][192]; QTinv frags
__global__ __launch_bounds__(256) void ki(const float* __restrict__ lam,
    const float* __restrict__ cin, const float* __restrict__ c0,
    const float* __restrict__ Qinv, float* __restrict__ S0, float* __restrict__ C0,
    unsigned short* __restrict__ xh, unsigned short* __restrict__ xl,
    unsigned short* __restrict__ QTh, unsigned short* __restrict__ QTl) {
  int idx = blockIdx.x*256 + threadIdx.x;
  if (idx < NV*B2) {
    int j = idx / B2, s = idx - j*B2;
    S0[idx] = lam[(size_t)s*576 + j] + lam[(size_t)s*576 + 192 + j]
            + lam[(size_t)s*576 + 384 + j] + cin[(size_t)s*NV + j];
    return;
  }
  idx -= NV*B2;
  if (idx < NV*B2) { int i = idx / B2, s = idx - i*B2; C0[idx] = c0[(size_t)s*NV + i]; return; }
  idx -= NV*B2;
  if (idx < NV*B2) {
    unsigned short h,l; bsplit2(c0[idx], h, l);   // same [s][192] linear layout
    xh[idx]=h; xl[idx]=l;
    return;
  }
  idx -= NV*B2;
  if (idx < 12*7*512) {
    int jj = idx&7, lane=(idx>>3)&63, kb=(idx>>9)%7, mb=(idx>>9)/7;
    int i = mb*16 + (lane&15), j = kb*32 + (lane>>4)*8 + jj;
    float v = (j < NTT) ? Qinv[(size_t)i*NTT + j] : 0.f;
    unsigned short h,l; bsplit2(v,h,l);
    QTh[idx]=h; QTl[idx]=l;
  }
}

// A operand swizzle (validated r2/r4/r6)
__global__ __launch_bounds__(256) void kA(const float* __restrict__ Av,
    const float* __restrict__ Aa, const float* __restrict__ Ap,
    unsigned short* __restrict__ Ah, unsigned short* __restrict__ Al,
    unsigned short* __restrict__ Ath, unsigned short* __restrict__ Atl) {
  int idx = blockIdx.x*256 + threadIdx.x;
  const int HALF = 3*80*6*512;
  if (idx >= 2*HALF) return;
  if (idx < HALF) {
    int j = idx&7, lane=(idx>>3)&63, kb=(idx>>9)%6, rb=(idx>>9)/6%80, mat=idx/(80*6*512);
    int row = rb*16 + (lane&15), col = kb*32 + (lane>>4)*8 + j;
    const float* A = (mat==0)?Av:((mat==1)?Aa:Ap);
    float v = (row < 1200) ? A[(size_t)row*NV + col] : 0.f;
    unsigned short h,l; bsplit2(v,h,l); Ah[idx]=h; Al[idx]=l;
  } else {
    int oi = idx - HALF;
    int jj = oi&7, lane=(oi>>3)&63, kbr=(oi>>9)%40, cb=(oi>>9)/40%12, mat=oi/(12*40*512);
    int row = kbr*32 + (lane>>4)*8 + jj, col = cb*16 + (lane&15);
    const float* A = (mat==0)?Av:((mat==1)?Aa:Ap);
    float v = (row < 1200) ? A[(size_t)row*NV + col] : 0.f;
    unsigned short h,l; bsplit2(v,h,l); Ath[oi]=h; Atl[oi]=l;
  }
}

// ---- kP: per-tile solve. grid = 128, block = 512. ----
__global__ __launch_bounds__(512) void kP(
    const float* __restrict__ Sin, float* __restrict__ Sout,
    const float* __restrict__ Cin, float* __restrict__ Cout,
    const float* __restrict__ beq,
    const float* __restrict__ dl, const float* __restrict__ sqP,
    unsigned short* __restrict__ xh, unsigned short* __restrict__ xl,
    const unsigned short* __restrict__ QTh, const unsigned short* __restrict__ QTl,
    const unsigned short* __restrict__ Mh, const unsigned short* __restrict__ Ml,
    float* __restrict__ tot, int upd)
{
  __shared__ unsigned short rhsH[16*KPAD], rhsL[16*KPAD];
  __shared__ float mxL[16*PMX];
  __shared__ float lamAcc[64];   // [0..47] dl-norm partials, [48..63] xdiff
  const int tid = threadIdx.x, wave = tid>>6, lane = tid&63;
  const int n = lane&15, q = lane>>4;
  const int tile0 = blockIdx.x*16, ts = tile0+n;

  if (tid<64) lamAcc[tid] = 0.f;

  // x_{t-1} frags from stored split
  s16x8 xfh[6], xfl[6];
  {
    const size_t xo = (size_t)ts*NV + q*8;
    #pragma unroll
    for (int kb=0;kb<6;++kb) {
      xfh[kb] = *(const s16x8*)(xh + xo + kb*32);
      xfl[kb] = *(const s16x8*)(xl + xo + kb*32);
    }
  }
  __syncthreads();
  // Mall * x
  #pragma unroll 1
  for (int mi=0;mi<2;++mi) {
    const int mb = wave + mi*8;
    if (mb>=12) break;
    f32x4 a0={0,0,0,0}, a1={0,0,0,0}, a2={0,0,0,0};
    #pragma unroll
    for (int kb=0;kb<6;++kb) {
      s16x8 mh = *(const s16x8*)(Mh + ((size_t)(mb*6+kb))*512 + lane*8);
      s16x8 ml = *(const s16x8*)(Ml + ((size_t)(mb*6+kb))*512 + lane*8);
      a0 = MFMA(mh, xfh[kb], a0);
      a1 = MFMA(mh, xfl[kb], a1);
      a2 = MFMA(ml, xfh[kb], a2);
    }
    #pragma unroll
    for (int r=0;r<4;++r) mxL[n*PMX + mb*16 + q*4 + r] = a0[r]+a1[r]+a2[r];
  }
  __syncthreads();
  // dl sums, S update, rhs build, lambda-norm partials
  {
    const int s = tid & 15, jg = tid >> 4;
    const int sg = tile0 + s;
    float l0=0.f, l1=0.f, l2=0.f;
    #pragma unroll 1
    for (int jp=0;jp<6;++jp) {
      const int j = jg + jp*32;
      float dm0=0.f, dm1=0.f, dm2=0.f;
      #pragma unroll
      for (int c=0;c<4;++c) {
        dm0 += dl[((size_t)c*576 + j)*B2 + sg];
        dm1 += dl[((size_t)c*576 + NV + j)*B2 + sg];
        dm2 += dl[((size_t)c*576 + 2*NV + j)*B2 + sg];
      }
      const float dsum = dm0+dm1+dm2;
      const float Sc = Sin[(size_t)j*B2 + sg];
      const float Sn = upd ? (Sc - dsum) : Sc;   // d=1: dl_0 is G-only, no lam update
      Sout[(size_t)j*B2 + sg] = Sn;
      const float rv = Sn + mxL[s*PMX + j] - dsum;   // = S_new + G
      unsigned short h,l; bsplit2(rv,h,l);
      rhsH[s*KPAD + j] = h; rhsL[s*KPAD + j] = l;
      l0 += dm0*dm0; l1 += dm1*dm1; l2 += dm2*dm2;
    }
    l0 += __shfl_xor(l0,16); l0 += __shfl_xor(l0,32);
    l1 += __shfl_xor(l1,16); l1 += __shfl_xor(l1,32);
    l2 += __shfl_xor(l2,16); l2 += __shfl_xor(l2,32);
    if (q==0 && upd) {
      atomicAdd(&lamAcc[n], l0);
      atomicAdd(&lamAcc[16+n], l1);
      atomicAdd(&lamAcc[32+n], l2);
    }
  }
  if (tid < 480) {
    const int je = tid>>4, sB = tid&15;
    unsigned short h,l; bsplit2(beq[(size_t)(tile0+sB)*30 + je], h, l);
    rhsH[sB*KPAD + NV + je] = h; rhsL[sB*KPAD + NV + je] = l;
  }
  if (tid < 160) {   // zero pad j = 222..231
    const int sB = tid&15, jt = NTT + (tid>>4);
    rhsH[sB*KPAD + jt] = 0; rhsL[sB*KPAD + jt] = 0;
  }
  __syncthreads();
  // Qinv MFMA -> primal
  s16x8 rfh[7], rfl[7];
  #pragma unroll
  for (int kb=0;kb<7;++kb) {
    rfh[kb] = *(const s16x8*)(rhsH + n*KPAD + kb*32 + q*8);
    rfl[kb] = *(const s16x8*)(rhsL + n*KPAD + kb*32 + q*8);
  }
  float xdl = 0.f;
  #pragma unroll 1
  for (int mi=0;mi<2;++mi) {
    const int mb = wave + mi*8;
    if (mb>=12) break;
    f32x4 a0={0,0,0,0}, a1={0,0,0,0}, a2={0,0,0,0};
    #pragma unroll
    for (int kb=0;kb<7;++kb) {
      s16x8 qh = *(const s16x8*)(QTh + ((size_t)(mb*7+kb))*512 + lane*8);
      s16x8 ql = *(const s16x8*)(QTl + ((size_t)(mb*7+kb))*512 + lane*8);
      a0 = MFMA(qh, rfh[kb], a0);
      a1 = MFMA(qh, rfl[kb], a1);
      a2 = MFMA(ql, rfh[kb], a2);
    }
    unsigned short xh4[4], xl4[4];
    #pragma unroll
    for (int r=0;r<4;++r) {
      const float xv = a0[r]+a1[r]+a2[r];
      const int i = mb*16 + q*4 + r;
      const float df = xv - Cin[(size_t)i*B2 + ts];
      xdl += df*df;
      Cout[(size_t)i*B2 + ts] = xv;
      bsplit2(xv, xh4[r], xl4[r]);
    }
    uint2 pk;
    pk.x = (unsigned)xh4[0] | ((unsigned)xh4[1]<<16);
    pk.y = (unsigned)xh4[2] | ((unsigned)xh4[3]<<16);
    *(uint2*)(xh + (size_t)ts*NV + mb*16 + q*4) = pk;
    pk.x = (unsigned)xl4[0] | ((unsigned)xl4[1]<<16);
    pk.y = (unsigned)xl4[2] | ((unsigned)xl4[3]<<16);
    *(uint2*)(xl + (size_t)ts*NV + mb*16 + q*4) = pk;
  }
  xdl += __shfl_xor(xdl,16); xdl += __shfl_xor(xdl,32);
  if (q==0) atomicAdd(&lamAcc[48+n], xdl);
  __syncthreads();
  // finalize tot: ||dl_{t-1}|| (upd) + res/sd_{t-1} (sqP; skipped at d=1) + xdiff_t
  if (tid < 16) {
    const int sg2 = tile0 + tid;
    float fp = sqrtf(lamAcc[tid]) + sqrtf(lamAcc[16+tid])
             + sqrtf(lamAcc[32+tid]) + sqrtf(lamAcc[48+tid]);
    float rp = 0.f;
    if (upd) {
      #pragma unroll
      for (int sl=0;sl<6;++sl) {
        float v = sqP[(size_t)sg2*8+sl] + sqP[16384+(size_t)sg2*8+sl]
                + sqP[2*16384+(size_t)sg2*8+sl] + sqP[3*16384+(size_t)sg2*8+sl];
        float nn = sqrtf(v);
        if (sl<3) rp += nn; else fp += nn;
      }
      tot[(size_t)sg2*2+0] += fp;
      tot[(size_t)sg2*2+1] += rp;
    } else {
      tot[(size_t)sg2*2+0] = fp;   // first iteration: initialize (ws is poisoned)
      tot[(size_t)sg2*2+1] = 0.f;
    }
  }
}

// ---- k2: A-streamer. grid = 512 (blockIdx = tile*4+chunk), block = 512. ----
template<int FIRST>
__global__ __launch_bounds__(512) void k2(
    const unsigned short* __restrict__ Ah, const unsigned short* __restrict__ Al,
    const unsigned short* __restrict__ Ath, const unsigned short* __restrict__ Atl,
    const unsigned short* __restrict__ xh, const unsigned short* __restrict__ xl,
    __half* __restrict__ uW, float* __restrict__ dl, float* __restrict__ sqP)
{
  __shared__ unsigned short rsh[16*PR], rsl[16*PR];
  __shared__ float sqAcc[96];
  const int tid = threadIdx.x, wave = tid>>6, lane = tid&63;
  const int n = lane&15, q = lane>>4;
  const int tile = blockIdx.x >> 2, chunk = blockIdx.x & 3;
  const int tile0 = tile*16, ts = tile0 + n;

  if (tid < 96) sqAcc[tid] = 0.f;

  s16x8 xfh[6], xfl[6];
  {
    const size_t xo = (size_t)ts*NV + q*8;
    #pragma unroll
    for (int kb=0;kb<6;++kb) {
      xfh[kb] = *(const s16x8*)(xh + xo + kb*32);
      xfl[kb] = *(const s16x8*)(xl + xo + kb*32);
    }
  }
  __syncthreads();

  #pragma unroll 1
  for (int mat=0; mat<3; ++mat) {
    const float b = (mat==0)?0.8f:((mat==1)?1.8f:3.14159265358979f);
    if (mat>0) __syncthreads();
    float rsq=0.f, ssq=0.f;
    // fwd: v = A x, rs/u
    #pragma unroll 1
    for (int ri=0; ri<3; ++ri) {
      const int rbl = wave + ri*8;
      if (rbl >= 20) break;
      const int rb = chunk*20 + rbl;
      f32x4 a0={0,0,0,0}, a1={0,0,0,0}, a2={0,0,0,0};
      const size_t ab = ((size_t)(mat*80+rb)*6)*512 + (size_t)lane*8;
      #pragma unroll
      for (int kb=0;kb<6;++kb) {
        s16x8 ah = *(const s16x8*)(Ah + ab + (size_t)kb*512);
        s16x8 al = *(const s16x8*)(Al + ab + (size_t)kb*512);
        a0 = MFMA(ah, xfh[kb], a0);
        a1 = MFMA(ah, xfl[kb], a1);
        a2 = MFMA(al, xfh[kb], a2);
      }
      unsigned short rh4[4], rl4[4];
      #pragma unroll
      for (int r4i=0;r4i<4;++r4i) {
        const float v = a0[r4i]+a1[r4i]+a2[r4i];
        const float rs = fmaxf(v-b, 0.f);
        const int r = rb*16 + q*4 + r4i;
        if (r < 1200) {
          const float u = fminf(v, b);
          const size_t ui = ((size_t)mat*1200 + r)*B2 + ts;
          if (!FIRST) {
            const float sd = u - __half2float(uW[ui]);
            ssq += sd*sd; rsq += rs*rs;
          }
          uW[ui] = __float2half(u);
        }
        bsplit2(rs, rh4[r4i], rl4[r4i]);
      }
      const int lo = n*PR + rbl*16 + q*4;
      uint2 pk;
      pk.x = (unsigned)rh4[0] | ((unsigned)rh4[1]<<16);
      pk.y = (unsigned)rh4[2] | ((unsigned)rh4[3]<<16);
      *(uint2*)(rsh + lo) = pk;
      pk.x = (unsigned)rl4[0] | ((unsigned)rl4[1]<<16);
      pk.y = (unsigned)rl4[2] | ((unsigned)rl4[3]<<16);
      *(uint2*)(rsl + lo) = pk;
    }
    if (!FIRST) {
      rsq += __shfl_xor(rsq,16); rsq += __shfl_xor(rsq,32);
      ssq += __shfl_xor(ssq,16); ssq += __shfl_xor(ssq,32);
      if (q==0) {
        atomicAdd(&sqAcc[mat*16+n], rsq);
        atomicAdd(&sqAcc[(3+mat)*16+n], ssq);
      }
    }
    __syncthreads();
    // transpose: dl = A^T rs  (also in prime: dl_0 is needed for G_1)
    #pragma unroll 1
    for (int ci=0; ci<2; ++ci) {
      const int cb = wave + ci*8;
      if (cb >= 12) break;
      f32x4 a0={0,0,0,0}, a1={0,0,0,0}, a2={0,0,0,0};
      const size_t tb = ((size_t)((mat*12+cb)*40) + chunk*10)*512 + (size_t)lane*8;
      const int lb = n*PR + q*8;
      #pragma unroll 2
      for (int kk=0;kk<10;++kk) {
        s16x8 th = *(const s16x8*)(Ath + tb + (size_t)kk*512);
        s16x8 tl = *(const s16x8*)(Atl + tb + (size_t)kk*512);
        s16x8 rh = *(const s16x8*)(rsh + lb + kk*32);
        s16x8 rl = *(const s16x8*)(rsl + lb + kk*32);
        a0 = MFMA(th, rh, a0);
        a1 = MFMA(th, rl, a1);
        a2 = MFMA(tl, rh, a2);
      }
      #pragma unroll
      for (int r4i=0;r4i<4;++r4i)
        dl[((size_t)chunk*576 + mat*NV + cb*16 + q*4 + r4i)*B2 + ts] = a0[r4i]+a1[r4i]+a2[r4i];
    }
  }
  __syncthreads();
  if (!FIRST && tid<96) {
    int s = tid&15, sl = tid>>4;
    sqP[(size_t)chunk*16384 + (size_t)(tile0+s)*8 + sl] = sqAcc[sl*16+s];
  }
}

// finalize iteration-15 norms + outputs
__global__ __launch_bounds__(256) void k3(const float* __restrict__ dl,
    const float* __restrict__ sqP, const float* __restrict__ Cfin,
    const float* __restrict__ tot, float* __restrict__ out)
{
  __shared__ float sqL[8][4];
  const int tid = threadIdx.x;
  const int sb = blockIdx.x*8;
  if (tid<32) ((float*)sqL)[tid]=0.f;
  __syncthreads();
  for (int idx=tid; idx<8*576; idx+=256) {
    int s = idx&7, e = idx>>3;
    float v = 0.f;
    #pragma unroll
    for (int c=0;c<4;++c) v += dl[((size_t)c*576 + e)*B2 + sb + s];
    atomicAdd(&sqL[s][e/NV], v*v);
  }
  for (int idx=tid; idx<8*NV; idx+=256) {
    int s = idx/NV, i = idx - s*NV;
    out[(size_t)(sb+s)*NV + i] = Cfin[(size_t)i*B2 + sb + s];
  }
  __syncthreads();
  if (tid<8) {
    int s = tid, sg = sb+s;
    float fp = sqrtf(sqL[s][0]) + sqrtf(sqL[s][1]) + sqrtf(sqL[s][2]);
    float rp = 0.f;
    #pragma unroll
    for (int sl=0;sl<6;++sl) {
      float v = sqP[(size_t)sg*8+sl] + sqP[16384+(size_t)sg*8+sl]
              + sqP[2*16384+(size_t)sg*8+sl] + sqP[3*16384+(size_t)sg*8+sl];
      float nn = sqrtf(v);
      if (sl<3) rp += nn; else fp += nn;
    }
    fp += tot[(size_t)sg*2+0];
    rp += tot[(size_t)sg*2+1];
    out[(size_t)B2*NV + sg] = fp * (1.f/15.f);
    out[(size_t)B2*NV + B2 + sg] = rp * (1.f/15.f);
  }
}

extern "C" void kernel_launch(void* const* d_in, const int* in_sizes, int n_in,
                              void* d_out, int out_size, void* d_ws, size_t ws_size,
                              hipStream_t stream) {
  const float* lamda = (const float*)d_in[0];
  const float* cin   = (const float*)d_in[1];
  const float* c0    = (const float*)d_in[2];
  const float* beq   = (const float*)d_in[3];
  const float* Av    = (const float*)d_in[4];
  const float* Aa    = (const float*)d_in[5];
  const float* Ap    = (const float*)d_in[6];
  const float* Qinv  = (const float*)d_in[7];
  if (ws_size < (size_t)WS_FLOATS * sizeof(float)) return;

  float* ws = (float*)d_ws;
  float* S[2]  = { ws + O_S0, ws + O_S1 };
  float* C[2]  = { ws + O_C0, ws + O_C1 };
  __half* uW   = (__half*)(ws + O_U);
  float* dl    = ws + O_DL;
  float* sqP   = ws + O_SQP;
  float* tot   = ws + O_TOT;
  unsigned short* xh  = (unsigned short*)(ws + O_XH);
  unsigned short* xl  = (unsigned short*)(ws + O_XL);
  unsigned short* Ah  = (unsigned short*)(ws + O_AH);
  unsigned short* Al  = (unsigned short*)(ws + O_AL);
  unsigned short* Ath = (unsigned short*)(ws + O_ATH);
  unsigned short* Atl = (unsigned short*)(ws + O_ATL);
  unsigned short* QTh = (unsigned short*)(ws + O_QTH);
  unsigned short* QTl = (unsigned short*)(ws + O_QTL);
  unsigned short* Mh  = (unsigned short*)(ws + O_MH);
  unsigned short* Ml  = (unsigned short*)(ws + O_ML2);
  float* MP = ws + O_MP;
  float* out = (float*)d_out;

  kM<<<4*144, 256, 0, stream>>>(Av, Aa, Ap, MP);
  kS<<<144, 256, 0, stream>>>(MP, Mh, Ml);
  ki<<<(3*NV*B2 + 12*7*512 + 255)/256, 256, 0, stream>>>(lamda, cin, c0, Qinv,
      S[0], C[0], xh, xl, QTh, QTl);
  kA<<<(2*3*80*6*512 + 255)/256, 256, 0, stream>>>(Av, Aa, Ap, Ah, Al, Ath, Atl);

  // prime: u_0 and dl_0 = A^T relu(A c0 - b) from x = c0
  k2<1><<<512, 512, 0, stream>>>(Ah, Al, Ath, Atl, xh, xl, uW, dl, sqP);
  for (int d = 1; d <= 15; ++d) {
    kP<<<128, 512, 0, stream>>>(S[(d+1)&1], S[d&1], C[(d+1)&1], C[d&1], beq,
        dl, sqP, xh, xl, QTh, QTl, Mh, Ml, tot, (d>=2)?1:0);
    k2<0><<<512, 512, 0, stream>>>(Ah, Al, Ath, Atl, xh, xl, uW, dl, sqP);
  }
  k3<<<256, 256, 0, stream>>>(dl, sqP, C[1], tot, out);
}

// Round 8
// 1312.386 us; speedup vs baseline: 3.0641x; 1.0365x over previous
//
#include <hip/hip_runtime.h>
#include <hip/hip_fp16.h>

// MLPProjectionFilter round 8 = round-7 (deterministic, validated) with:
//  - k2 MTILE 16->32: A-frags in registers feed two 16-sample MFMA groups;
//    WG count halves -> A-fragment L2/L3 traffic halves (was ~755 MB/dispatch).
//  - kM: 48 deterministic row-partials (75 rows, 3 independent FMA chains)
//    instead of 4 partials with a 900-long dependent chain; kS sums fixed-order.
// Per iter: kP (per-tile: dl-sum, S/lambda, G=Mall*x-dlsum, rhs, Qinv MFMA,
// norms) then k2 (A-stream: v=Ax fwd + dl=A^T rs transpose, split-bf16 MFMA).

typedef short s16x8 __attribute__((ext_vector_type(8)));
typedef float f32x4 __attribute__((ext_vector_type(4)));
#define MFMA(a,b,c) __builtin_amdgcn_mfma_f32_16x16x32_bf16(a,b,c,0,0,0)

#define B2 2048
#define NV 192
#define NTT 222
#define KPAD 232
#define PR 328        // k2 rs LDS pitch (ushort), 320 rows/chunk + pad
#define PMX 200       // kP mxL pitch (f32)
#define NPART 48      // Gram partials

// ---- ws layout (float offsets) ----
#define O_S0  0u
#define O_S1  393216u
#define O_C0  786432u
#define O_C1  1179648u
#define O_U   1572864u     // __half[3*1200*2048] = 3,686,400 fl
#define O_DL  5259264u     // f32 [4][576][2048] = 4,718,592
#define O_SQP 9977856u     // f32 [4][2048][8] = 65,536
#define O_TOT 10043392u    // f32 [2048][2] = 4,096
#define O_XH  10047488u    // ushort[2048*192] = 196,608 fl
#define O_XL  10244096u
#define O_AH  10440704u    // ushort[3*80*6*512] = 368,640 fl each
#define O_AL  10809344u
#define O_ATH 11177984u
#define O_ATL 11546624u
#define O_QTH 11915264u    // ushort[12*7*512] = 21,504 fl
#define O_QTL 11936768u
#define O_MH  11958272u    // ushort[12*6*512] = 18,432 fl
#define O_ML2 11976704u
#define O_MP  11995136u    // f32 [48][192*192] Gram partials = 1,769,472
#define WS_FLOATS 13764608u  // 55.1 MB

__device__ inline unsigned short bh16(float v){
  union{float f; unsigned u;} a; a.f=v;
  return (unsigned short)((a.u + 0x7FFFu + ((a.u>>16)&1u))>>16);
}
__device__ inline void bsplit2(float v, unsigned short& h, unsigned short& l){
  h = bh16(v);
  union{unsigned u; float f;} hf; hf.u = ((unsigned)h)<<16;
  l = bh16(v - hf.f);
}

// Gram partials: MP[part][i*NV+j], part = mat*16 + rblk, rows [rblk*75, +75).
// Deterministic (no atomics), 3 independent FMA chains.
__global__ __launch_bounds__(256) void kM(const float* __restrict__ Av,
    const float* __restrict__ Aa, const float* __restrict__ Ap, float* __restrict__ MP) {
  int bb = blockIdx.x % 144, part = blockIdx.x / 144;
  int idx = bb*256 + threadIdx.x;
  if (idx >= NV*NV) return;
  int i = idx / NV, j = idx - i*NV;
  const int mat = part >> 4;
  const float* __restrict__ A = (mat==0)?Av:((mat==1)?Aa:Ap);
  const int r0 = (part & 15) * 75;
  float a0=0.f, a1=0.f, a2=0.f;
  #pragma unroll 5
  for (int r=r0; r<r0+75; r+=3) {
    a0 = fmaf(A[(size_t)r*NV+i],     A[(size_t)r*NV+j],     a0);
    a1 = fmaf(A[(size_t)(r+1)*NV+i], A[(size_t)(r+1)*NV+j], a1);
    a2 = fmaf(A[(size_t)(r+2)*NV+i], A[(size_t)(r+2)*NV+j], a2);
  }
  MP[(size_t)part*NV*NV + idx] = (a0 + a1) + a2;
}

// sum Gram partials (fixed order) and swizzle into MFMA A-frags (bf16 hi/lo)
__global__ __launch_bounds__(256) void kS(const float* __restrict__ MP,
    unsigned short* __restrict__ Mh, unsigned short* __restrict__ Ml) {
  int idx = blockIdx.x*256 + threadIdx.x;
  if (idx >= 12*6*512) return;
  int jj = idx&7, lane=(idx>>3)&63, kb=(idx>>9)%6, mb=(idx>>9)/6;
  int i = mb*16 + (lane&15), k = kb*32 + (lane>>4)*8 + jj;
  const size_t e = (size_t)i*NV + k;
  float v = 0.f;
  #pragma unroll
  for (int p=0;p<NPART;++p) v += MP[(size_t)p*NV*NV + e];
  unsigned short h,l; bsplit2(v, h, l);
  Mh[idx]=h; Ml[idx]=l;
}

// init: S0 = lamv+lama+lamp+cin [192][2048]; C0 = c0^T [192][2048];
// xh/xl = split(c0) [s][192]; QTinv frags
__global__ __launch_bounds__(256) void ki(const float* __restrict__ lam,
    const float* __restrict__ cin, const float* __restrict__ c0,
    const float* __restrict__ Qinv, float* __restrict__ S0, float* __restrict__ C0,
    unsigned short* __restrict__ xh, unsigned short* __restrict__ xl,
    unsigned short* __restrict__ QTh, unsigned short* __restrict__ QTl) {
  int idx = blockIdx.x*256 + threadIdx.x;
  if (idx < NV*B2) {
    int j = idx / B2, s = idx - j*B2;
    S0[idx] = lam[(size_t)s*576 + j] + lam[(size_t)s*576 + 192 + j]
            + lam[(size_t)s*576 + 384 + j] + cin[(size_t)s*NV + j];
    return;
  }
  idx -= NV*B2;
  if (idx < NV*B2) { int i = idx / B2, s = idx - i*B2; C0[idx] = c0[(size_t)s*NV + i]; return; }
  idx -= NV*B2;
  if (idx < NV*B2) {
    unsigned short h,l; bsplit2(c0[idx], h, l);   // same [s][192] linear layout
    xh[idx]=h; xl[idx]=l;
    return;
  }
  idx -= NV*B2;
  if (idx < 12*7*512) {
    int jj = idx&7, lane=(idx>>3)&63, kb=(idx>>9)%7, mb=(idx>>9)/7;
    int i = mb*16 + (lane&15), j = kb*32 + (lane>>4)*8 + jj;
    float v = (j < NTT) ? Qinv[(size_t)i*NTT + j] : 0.f;
    unsigned short h,l; bsplit2(v,h,l);
    QTh[idx]=h; QTl[idx]=l;
  }
}

// A operand swizzle (validated r2/r4/r6/r7)
__global__ __launch_bounds__(256) void kA(const float* __restrict__ Av,
    const float* __restrict__ Aa, const float* __restrict__ Ap,
    unsigned short* __restrict__ Ah, unsigned short* __restrict__ Al,
    unsigned short* __restrict__ Ath, unsigned short* __restrict__ Atl) {
  int idx = blockIdx.x*256 + threadIdx.x;
  const int HALF = 3*80*6*512;
  if (idx >= 2*HALF) return;
  if (idx < HALF) {
    int j = idx&7, lane=(idx>>3)&63, kb=(idx>>9)%6, rb=(idx>>9)/6%80, mat=idx/(80*6*512);
    int row = rb*16 + (lane&15), col = kb*32 + (lane>>4)*8 + j;
    const float* A = (mat==0)?Av:((mat==1)?Aa:Ap);
    float v = (row < 1200) ? A[(size_t)row*NV + col] : 0.f;
    unsigned short h,l; bsplit2(v,h,l); Ah[idx]=h; Al[idx]=l;
  } else {
    int oi = idx - HALF;
    int jj = oi&7, lane=(oi>>3)&63, kbr=(oi>>9)%40, cb=(oi>>9)/40%12, mat=oi/(12*40*512);
    int row = kbr*32 + (lane>>4)*8 + jj, col = cb*16 + (lane&15);
    const float* A = (mat==0)?Av:((mat==1)?Aa:Ap);
    float v = (row < 1200) ? A[(size_t)row*NV + col] : 0.f;
    unsigned short h,l; bsplit2(v,h,l); Ath[oi]=h; Atl[oi]=l;
  }
}

// ---- kP: per-tile solve. grid = 128, block = 512. (unchanged from r7) ----
__global__ __launch_bounds__(512) void kP(
    const float* __restrict__ Sin, float* __restrict__ Sout,
    const float* __restrict__ Cin, float* __restrict__ Cout,
    const float* __restrict__ beq,
    const float* __restrict__ dl, const float* __restrict__ sqP,
    unsigned short* __restrict__ xh, unsigned short* __restrict__ xl,
    const unsigned short* __restrict__ QTh, const unsigned short* __restrict__ QTl,
    const unsigned short* __restrict__ Mh, const unsigned short* __restrict__ Ml,
    float* __restrict__ tot, int upd)
{
  __shared__ unsigned short rhsH[16*KPAD], rhsL[16*KPAD];
  __shared__ float mxL[16*PMX];
  __shared__ float lamAcc[64];   // [0..47] dl-norm partials, [48..63] xdiff
  const int tid = threadIdx.x, wave = tid>>6, lane = tid&63;
  const int n = lane&15, q = lane>>4;
  const int tile0 = blockIdx.x*16, ts = tile0+n;

  if (tid<64) lamAcc[tid] = 0.f;

  s16x8 xfh[6], xfl[6];
  {
    const size_t xo = (size_t)ts*NV + q*8;
    #pragma unroll
    for (int kb=0;kb<6;++kb) {
      xfh[kb] = *(const s16x8*)(xh + xo + kb*32);
      xfl[kb] = *(const s16x8*)(xl + xo + kb*32);
    }
  }
  __syncthreads();
  // Mall * x
  #pragma unroll 1
  for (int mi=0;mi<2;++mi) {
    const int mb = wave + mi*8;
    if (mb>=12) break;
    f32x4 a0={0,0,0,0}, a1={0,0,0,0}, a2={0,0,0,0};
    #pragma unroll
    for (int kb=0;kb<6;++kb) {
      s16x8 mh = *(const s16x8*)(Mh + ((size_t)(mb*6+kb))*512 + lane*8);
      s16x8 ml = *(const s16x8*)(Ml + ((size_t)(mb*6+kb))*512 + lane*8);
      a0 = MFMA(mh, xfh[kb], a0);
      a1 = MFMA(mh, xfl[kb], a1);
      a2 = MFMA(ml, xfh[kb], a2);
    }
    #pragma unroll
    for (int r=0;r<4;++r) mxL[n*PMX + mb*16 + q*4 + r] = a0[r]+a1[r]+a2[r];
  }
  __syncthreads();
  // dl sums, S update, rhs build, lambda-norm partials
  {
    const int s = tid & 15, jg = tid >> 4;
    const int sg = tile0 + s;
    float l0=0.f, l1=0.f, l2=0.f;
    #pragma unroll 1
    for (int jp=0;jp<6;++jp) {
      const int j = jg + jp*32;
      float dm0=0.f, dm1=0.f, dm2=0.f;
      #pragma unroll
      for (int c=0;c<4;++c) {
        dm0 += dl[((size_t)c*576 + j)*B2 + sg];
        dm1 += dl[((size_t)c*576 + NV + j)*B2 + sg];
        dm2 += dl[((size_t)c*576 + 2*NV + j)*B2 + sg];
      }
      const float dsum = dm0+dm1+dm2;
      const float Sc = Sin[(size_t)j*B2 + sg];
      const float Sn = upd ? (Sc - dsum) : Sc;   // d=1: dl_0 is G-only, no lam update
      Sout[(size_t)j*B2 + sg] = Sn;
      const float rv = Sn + mxL[s*PMX + j] - dsum;   // = S_new + G
      unsigned short h,l; bsplit2(rv,h,l);
      rhsH[s*KPAD + j] = h; rhsL[s*KPAD + j] = l;
      l0 += dm0*dm0; l1 += dm1*dm1; l2 += dm2*dm2;
    }
    l0 += __shfl_xor(l0,16); l0 += __shfl_xor(l0,32);
    l1 += __shfl_xor(l1,16); l1 += __shfl_xor(l1,32);
    l2 += __shfl_xor(l2,16); l2 += __shfl_xor(l2,32);
    if (q==0 && upd) {
      atomicAdd(&lamAcc[n], l0);
      atomicAdd(&lamAcc[16+n], l1);
      atomicAdd(&lamAcc[32+n], l2);
    }
  }
  if (tid < 480) {
    const int je = tid>>4, sB = tid&15;
    unsigned short h,l; bsplit2(beq[(size_t)(tile0+sB)*30 + je], h, l);
    rhsH[sB*KPAD + NV + je] = h; rhsL[sB*KPAD + NV + je] = l;
  }
  if (tid < 160) {   // zero pad j = 222..231
    const int sB = tid&15, jt = NTT + (tid>>4);
    rhsH[sB*KPAD + jt] = 0; rhsL[sB*KPAD + jt] = 0;
  }
  __syncthreads();
  // Qinv MFMA -> primal
  s16x8 rfh[7], rfl[7];
  #pragma unroll
  for (int kb=0;kb<7;++kb) {
    rfh[kb] = *(const s16x8*)(rhsH + n*KPAD + kb*32 + q*8);
    rfl[kb] = *(const s16x8*)(rhsL + n*KPAD + kb*32 + q*8);
  }
  float xdl = 0.f;
  #pragma unroll 1
  for (int mi=0;mi<2;++mi) {
    const int mb = wave + mi*8;
    if (mb>=12) break;
    f32x4 a0={0,0,0,0}, a1={0,0,0,0}, a2={0,0,0,0};
    #pragma unroll
    for (int kb=0;kb<7;++kb) {
      s16x8 qh = *(const s16x8*)(QTh + ((size_t)(mb*7+kb))*512 + lane*8);
      s16x8 ql = *(const s16x8*)(QTl + ((size_t)(mb*7+kb))*512 + lane*8);
      a0 = MFMA(qh, rfh[kb], a0);
      a1 = MFMA(qh, rfl[kb], a1);
      a2 = MFMA(ql, rfh[kb], a2);
    }
    unsigned short xh4[4], xl4[4];
    #pragma unroll
    for (int r=0;r<4;++r) {
      const float xv = a0[r]+a1[r]+a2[r];
      const int i = mb*16 + q*4 + r;
      const float df = xv - Cin[(size_t)i*B2 + ts];
      xdl += df*df;
      Cout[(size_t)i*B2 + ts] = xv;
      bsplit2(xv, xh4[r], xl4[r]);
    }
    uint2 pk;
    pk.x = (unsigned)xh4[0] | ((unsigned)xh4[1]<<16);
    pk.y = (unsigned)xh4[2] | ((unsigned)xh4[3]<<16);
    *(uint2*)(xh + (size_t)ts*NV + mb*16 + q*4) = pk;
    pk.x = (unsigned)xl4[0] | ((unsigned)xl4[1]<<16);
    pk.y = (unsigned)xl4[2] | ((unsigned)xl4[3]<<16);
    *(uint2*)(xl + (size_t)ts*NV + mb*16 + q*4) = pk;
  }
  xdl += __shfl_xor(xdl,16); xdl += __shfl_xor(xdl,32);
  if (q==0) atomicAdd(&lamAcc[48+n], xdl);
  __syncthreads();
  // finalize tot: ||dl_{t-1}|| (upd) + res/sd_{t-1} (sqP; skipped at d=1) + xdiff_t
  if (tid < 16) {
    const int sg2 = tile0 + tid;
    float fp = sqrtf(lamAcc[tid]) + sqrtf(lamAcc[16+tid])
             + sqrtf(lamAcc[32+tid]) + sqrtf(lamAcc[48+tid]);
    float rp = 0.f;
    if (upd) {
      #pragma unroll
      for (int sl=0;sl<6;++sl) {
        float v = sqP[(size_t)sg2*8+sl] + sqP[16384+(size_t)sg2*8+sl]
                + sqP[2*16384+(size_t)sg2*8+sl] + sqP[3*16384+(size_t)sg2*8+sl];
        float nn = sqrtf(v);
        if (sl<3) rp += nn; else fp += nn;
      }
      tot[(size_t)sg2*2+0] += fp;
      tot[(size_t)sg2*2+1] += rp;
    } else {
      tot[(size_t)sg2*2+0] = fp;   // first iteration: initialize (ws is poisoned)
      tot[(size_t)sg2*2+1] = 0.f;
    }
  }
}

// ---- k2: A-streamer, MTILE=32. grid = 256 (blockIdx = tile*4+chunk), block = 512.
template<int FIRST>
__global__ __launch_bounds__(512) void k2(
    const unsigned short* __restrict__ Ah, const unsigned short* __restrict__ Al,
    const unsigned short* __restrict__ Ath, const unsigned short* __restrict__ Atl,
    const unsigned short* __restrict__ xh, const unsigned short* __restrict__ xl,
    __half* __restrict__ uW, float* __restrict__ dl, float* __restrict__ sqP)
{
  __shared__ unsigned short rsh[32*PR], rsl[32*PR];
  __shared__ float sqAcc[192];   // [slot 6][sample 32]
  const int tid = threadIdx.x, wave = tid>>6, lane = tid&63;
  const int n = lane&15, q = lane>>4;
  const int tile = blockIdx.x >> 2, chunk = blockIdx.x & 3;
  const int tile0 = tile*32;

  if (tid < 192) sqAcc[tid] = 0.f;

  // x B-frags for both 16-sample groups
  s16x8 xfh[2][6], xfl[2][6];
  #pragma unroll
  for (int g=0;g<2;++g) {
    const size_t xo = (size_t)(tile0 + g*16 + n)*NV + q*8;
    #pragma unroll
    for (int kb=0;kb<6;++kb) {
      xfh[g][kb] = *(const s16x8*)(xh + xo + kb*32);
      xfl[g][kb] = *(const s16x8*)(xl + xo + kb*32);
    }
  }
  __syncthreads();

  #pragma unroll 1
  for (int mat=0; mat<3; ++mat) {
    const float b = (mat==0)?0.8f:((mat==1)?1.8f:3.14159265358979f);
    if (mat>0) __syncthreads();
    float rsq[2]={0.f,0.f}, ssq[2]={0.f,0.f};
    // fwd: v = A x, rs/u — A-frags loaded once, used for both groups
    #pragma unroll 1
    for (int ri=0; ri<3; ++ri) {
      const int rbl = wave + ri*8;
      if (rbl >= 20) break;
      const int rb = chunk*20 + rbl;
      f32x4 acc[2][3];
      #pragma unroll
      for (int g=0;g<2;++g)
        #pragma unroll
        for (int p=0;p<3;++p) acc[g][p] = (f32x4){0.f,0.f,0.f,0.f};
      const size_t ab = ((size_t)(mat*80+rb)*6)*512 + (size_t)lane*8;
      #pragma unroll
      for (int kb=0;kb<6;++kb) {
        s16x8 ah = *(const s16x8*)(Ah + ab + (size_t)kb*512);
        s16x8 al = *(const s16x8*)(Al + ab + (size_t)kb*512);
        #pragma unroll
        for (int g=0;g<2;++g) {
          acc[g][0] = MFMA(ah, xfh[g][kb], acc[g][0]);
          acc[g][1] = MFMA(ah, xfl[g][kb], acc[g][1]);
          acc[g][2] = MFMA(al, xfh[g][kb], acc[g][2]);
        }
      }
      #pragma unroll
      for (int g=0;g<2;++g) {
        unsigned short rh4[4], rl4[4];
        #pragma unroll
        for (int r4i=0;r4i<4;++r4i) {
          const float v = acc[g][0][r4i]+acc[g][1][r4i]+acc[g][2][r4i];
          const float rs = fmaxf(v-b, 0.f);
          const int r = rb*16 + q*4 + r4i;
          if (r < 1200) {
            const float u = fminf(v, b);
            const size_t ui = ((size_t)mat*1200 + r)*B2 + tile0 + g*16 + n;
            if (!FIRST) {
              const float sd = u - __half2float(uW[ui]);
              ssq[g] += sd*sd; rsq[g] += rs*rs;
            }
            uW[ui] = __float2half(u);
          }
          bsplit2(rs, rh4[r4i], rl4[r4i]);
        }
        const int lo = (g*16+n)*PR + rbl*16 + q*4;
        uint2 pk;
        pk.x = (unsigned)rh4[0] | ((unsigned)rh4[1]<<16);
        pk.y = (unsigned)rh4[2] | ((unsigned)rh4[3]<<16);
        *(uint2*)(rsh + lo) = pk;
        pk.x = (unsigned)rl4[0] | ((unsigned)rl4[1]<<16);
        pk.y = (unsigned)rl4[2] | ((unsigned)rl4[3]<<16);
        *(uint2*)(rsl + lo) = pk;
      }
    }
    if (!FIRST) {
      #pragma unroll
      for (int g=0;g<2;++g) {
        float r1 = rsq[g], s1 = ssq[g];
        r1 += __shfl_xor(r1,16); r1 += __shfl_xor(r1,32);
        s1 += __shfl_xor(s1,16); s1 += __shfl_xor(s1,32);
        if (q==0) {
          atomicAdd(&sqAcc[mat*32 + g*16 + n], r1);
          atomicAdd(&sqAcc[(3+mat)*32 + g*16 + n], s1);
        }
      }
    }
    __syncthreads();
    // transpose: dl = A^T rs (A-frags reused across both groups)
    #pragma unroll 1
    for (int ci=0; ci<2; ++ci) {
      const int cb = wave + ci*8;
      if (cb >= 12) break;
      f32x4 dacc[2][3];
      #pragma unroll
      for (int g=0;g<2;++g)
        #pragma unroll
        for (int p=0;p<3;++p) dacc[g][p] = (f32x4){0.f,0.f,0.f,0.f};
      const size_t tb = ((size_t)((mat*12+cb)*40) + chunk*10)*512 + (size_t)lane*8;
      #pragma unroll 2
      for (int kk=0;kk<10;++kk) {
        s16x8 th = *(const s16x8*)(Ath + tb + (size_t)kk*512);
        s16x8 tl = *(const s16x8*)(Atl + tb + (size_t)kk*512);
        #pragma unroll
        for (int g=0;g<2;++g) {
          const int lb = (g*16+n)*PR + q*8 + kk*32;
          s16x8 rh = *(const s16x8*)(rsh + lb);
          s16x8 rl = *(const s16x8*)(rsl + lb);
          dacc[g][0] = MFMA(th, rh, dacc[g][0]);
          dacc[g][1] = MFMA(th, rl, dacc[g][1]);
          dacc[g][2] = MFMA(tl, rh, dacc[g][2]);
        }
      }
      #pragma unroll
      for (int g=0;g<2;++g)
        #pragma unroll
        for (int r4i=0;r4i<4;++r4i)
          dl[((size_t)chunk*576 + mat*NV + cb*16 + q*4 + r4i)*B2 + tile0 + g*16 + n]
            = dacc[g][0][r4i]+dacc[g][1][r4i]+dacc[g][2][r4i];
    }
  }
  __syncthreads();
  if (!FIRST && tid<192) {
    int s = tid & 31, sl = tid >> 5;
    sqP[(size_t)chunk*16384 + (size_t)(tile0+s)*8 + sl] = sqAcc[sl*32+s];
  }
}

// finalize iteration-15 norms + outputs
__global__ __launch_bounds__(256) void k3(const float* __restrict__ dl,
    const float* __restrict__ sqP, const float* __restrict__ Cfin,
    const float* __restrict__ tot, float* __restrict__ out)
{
  __shared__ float sqL[8][4];
  const int tid = threadIdx.x;
  const int sb = blockIdx.x*8;
  if (tid<32) ((float*)sqL)[tid]=0.f;
  __syncthreads();
  for (int idx=tid; idx<8*576; idx+=256) {
    int s = idx&7, e = idx>>3;
    float v = 0.f;
    #pragma unroll
    for (int c=0;c<4;++c) v += dl[((size_t)c*576 + e)*B2 + sb + s];
    atomicAdd(&sqL[s][e/NV], v*v);
  }
  for (int idx=tid; idx<8*NV; idx+=256) {
    int s = idx/NV, i = idx - s*NV;
    out[(size_t)(sb+s)*NV + i] = Cfin[(size_t)i*B2 + sb + s];
  }
  __syncthreads();
  if (tid<8) {
    int s = tid, sg = sb+s;
    float fp = sqrtf(sqL[s][0]) + sqrtf(sqL[s][1]) + sqrtf(sqL[s][2]);
    float rp = 0.f;
    #pragma unroll
    for (int sl=0;sl<6;++sl) {
      float v = sqP[(size_t)sg*8+sl] + sqP[16384+(size_t)sg*8+sl]
              + sqP[2*16384+(size_t)sg*8+sl] + sqP[3*16384+(size_t)sg*8+sl];
      float nn = sqrtf(v);
      if (sl<3) rp += nn; else fp += nn;
    }
    fp += tot[(size_t)sg*2+0];
    rp += tot[(size_t)sg*2+1];
    out[(size_t)B2*NV + sg] = fp * (1.f/15.f);
    out[(size_t)B2*NV + B2 + sg] = rp * (1.f/15.f);
  }
}

extern "C" void kernel_launch(void* const* d_in, const int* in_sizes, int n_in,
                              void* d_out, int out_size, void* d_ws, size_t ws_size,
                              hipStream_t stream) {
  const float* lamda = (const float*)d_in[0];
  const float* cin   = (const float*)d_in[1];
  const float* c0    = (const float*)d_in[2];
  const float* beq   = (const float*)d_in[3];
  const float* Av    = (const float*)d_in[4];
  const float* Aa    = (const float*)d_in[5];
  const float* Ap    = (const float*)d_in[6];
  const float* Qinv  = (const float*)d_in[7];
  if (ws_size < (size_t)WS_FLOATS * sizeof(float)) return;

  float* ws = (float*)d_ws;
  float* S[2]  = { ws + O_S0, ws + O_S1 };
  float* C[2]  = { ws + O_C0, ws + O_C1 };
  __half* uW   = (__half*)(ws + O_U);
  float* dl    = ws + O_DL;
  float* sqP   = ws + O_SQP;
  float* tot   = ws + O_TOT;
  unsigned short* xh  = (unsigned short*)(ws + O_XH);
  unsigned short* xl  = (unsigned short*)(ws + O_XL);
  unsigned short* Ah  = (unsigned short*)(ws + O_AH);
  unsigned short* Al  = (unsigned short*)(ws + O_AL);
  unsigned short* Ath = (unsigned short*)(ws + O_ATH);
  unsigned short* Atl = (unsigned short*)(ws + O_ATL);
  unsigned short* QTh = (unsigned short*)(ws + O_QTH);
  unsigned short* QTl = (unsigned short*)(ws + O_QTL);
  unsigned short* Mh  = (unsigned short*)(ws + O_MH);
  unsigned short* Ml  = (unsigned short*)(ws + O_ML2);
  float* MP = ws + O_MP;
  float* out = (float*)d_out;

  kM<<<NPART*144, 256, 0, stream>>>(Av, Aa, Ap, MP);
  kS<<<144, 256, 0, stream>>>(MP, Mh, Ml);
  ki<<<(3*NV*B2 + 12*7*512 + 255)/256, 256, 0, stream>>>(lamda, cin, c0, Qinv,
      S[0], C[0], xh, xl, QTh, QTl);
  kA<<<(2*3*80*6*512 + 255)/256, 256, 0, stream>>>(Av, Aa, Ap, Ah, Al, Ath, Atl);

  // prime: u_0 and dl_0 = A^T relu(A c0 - b) from x = c0
  k2<1><<<256, 512, 0, stream>>>(Ah, Al, Ath, Atl, xh, xl, uW, dl, sqP);
  for (int d = 1; d <= 15; ++d) {
    kP<<<128, 512, 0, stream>>>(S[(d+1)&1], S[d&1], C[(d+1)&1], C[d&1], beq,
        dl, sqP, xh, xl, QTh, QTl, Mh, Ml, tot, (d>=2)?1:0);
    k2<0><<<256, 512, 0, stream>>>(Ah, Al, Ath, Atl, xh, xl, uW, dl, sqP);
  }
  k3<<<256, 256, 0, stream>>>(dl, sqP, C[1], tot, out);
}